// Round 8
// baseline (485.308 us; speedup 1.0000x reference)
//
#include <hip/hip_runtime.h>
#include <math.h>

#define N_CH    256
#define SBSHIFT 11             // super-bucket = 2048 nodes
#define SBN     2048
#define NSMAX   64             // actual ns = 49
#define CH      4096           // edges per chunk (input and output chunks)

__device__ __forceinline__ float sigmoidf_(float v) {
    return 1.0f / (1.0f + expf(-v));
}

// ---- K1: blocks [0,nch) histogram one 4096-edge chunk into 49 coarse bins
// ---- (row -> H1, totals -> sbT); remaining blocks: per-node dots,
// ---- 4 waves/block x 8 nodes/wave with weights held in registers ----------
__global__ __launch_bounds__(256) void dots_hist_kernel(
    const float* __restrict__ x,
    const float* __restrict__ Wmlp, const float* __restrict__ Wlin,
    const float* __restrict__ Wgcn, const int* __restrict__ dst,
    float* __restrict__ s2dot, float* __restrict__ s3lin, float* __restrict__ xw,
    int* __restrict__ H1, int* __restrict__ sbT,
    int n_nodes, int n_edges, int ns, int nch)
{
    __shared__ int h[NSMAX];
    if ((int)blockIdx.x < nch) {
        int c = blockIdx.x;
        if (threadIdx.x < NSMAX) h[threadIdx.x] = 0;
        __syncthreads();
        int start = c * CH;
        #pragma unroll
        for (int m = 0; m < 4; ++m) {
            int e = start + (m * 256 + (int)threadIdx.x) * 4;
            if (e + 3 < n_edges) {
                int4 d4 = *(const int4*)(dst + e);
                atomicAdd(&h[d4.x >> SBSHIFT], 1);
                atomicAdd(&h[d4.y >> SBSHIFT], 1);
                atomicAdd(&h[d4.z >> SBSHIFT], 1);
                atomicAdd(&h[d4.w >> SBSHIFT], 1);
            } else {
                int eEnd = e + 4; if (eEnd > n_edges) eEnd = n_edges;
                for (int ee = e; ee < eEnd; ++ee)
                    atomicAdd(&h[dst[ee] >> SBSHIFT], 1);
            }
        }
        __syncthreads();
        if (threadIdx.x < NSMAX) {
            int v = (threadIdx.x < (unsigned)ns) ? h[threadIdx.x] : 0;
            H1[(size_t)c * NSMAX + threadIdx.x] = v;
            if (v) atomicAdd(&sbT[threadIdx.x], v);
        }
        return;
    }

    int wave = ((int)blockIdx.x - nch) * 4 + ((int)threadIdx.x >> 6);
    int lane = threadIdx.x & 63;
    int n0 = wave * 8;
    if (n0 >= n_nodes) return;
    float4 wm = ((const float4*)Wmlp)[lane];
    float4 wl = ((const float4*)Wlin)[lane];
    float4 wg = ((const float4*)Wgcn)[lane];
    int nEnd = n0 + 8; if (nEnd > n_nodes) nEnd = n_nodes;
    for (int node = n0; node < nEnd; ++node) {
        float4 v = ((const float4*)(x + (size_t)node * N_CH))[lane];
        float d0 = v.x*wm.x + v.y*wm.y + v.z*wm.z + v.w*wm.w;
        float d1 = v.x*wl.x + v.y*wl.y + v.z*wl.z + v.w*wl.w;
        float d2 = v.x*wg.x + v.y*wg.y + v.z*wg.z + v.w*wg.w;
        #pragma unroll
        for (int off = 32; off; off >>= 1) {
            d0 += __shfl_down(d0, off, 64);
            d1 += __shfl_down(d1, off, 64);
            d2 += __shfl_down(d2, off, 64);
        }
        if (lane == 0) { s2dot[node] = d0; s3lin[node] = d1; xw[node] = d2; }
    }
}

// ---- K2: tiny seed (1 block): sbs/cst tables, cursors, done counters --------
__global__ __launch_bounds__(64) void seed_kernel(
    const int* __restrict__ sbT, int* __restrict__ sbsG, int* __restrict__ cstG,
    int* __restrict__ cursor, int* __restrict__ doneD, int* __restrict__ doneF,
    int ns)
{
    __shared__ int sbsL[NSMAX + 1], cstL[NSMAX + 1];
    if (threadIdx.x == 0) {
        int run = 0, c = 0;
        for (int i = 0; i < ns; ++i) {
            sbsL[i] = run; cstL[i] = c;
            int len = sbT[i];
            run += len;
            int nc = (len + CH - 1) / CH; if (nc < 1) nc = 1;  // >=1 chunk/sb
            c += nc;
        }
        sbsL[ns] = run; cstL[ns] = c;
    }
    __syncthreads();
    int t = threadIdx.x;
    if (t <= ns) { sbsG[t] = sbsL[t]; cstG[t] = cstL[t]; }
    if (t < ns)  { cursor[t] = sbsL[t]; doneD[t] = 0; doneF[t] = 0; }
}

// ---- K3: scatter — H1-seeded LDS counting sort, cursor-reserved flush -------
// cpack word: src (17 bits) | local11 (11 bits) << 17
__global__ __launch_bounds__(256) void scatter_kernel(
    const int* __restrict__ src, const int* __restrict__ dst,
    const int* __restrict__ H1, int* __restrict__ cursor,
    int* __restrict__ cpack, int n_edges, int ns)
{
    __shared__ int lp[NSMAX + 1];      // local exclusive prefix
    __shared__ int h[NSMAX];           // rank counters
    __shared__ int pos0[NSMAX];        // reserved global base per sb
    __shared__ int sorted[CH];         // 16 KB

    int c = blockIdx.x;
    if (threadIdx.x < NSMAX) h[threadIdx.x] = H1[(size_t)c * NSMAX + threadIdx.x];
    __syncthreads();
    if (threadIdx.x == 0) {
        int run = 0;
        for (int i = 0; i < ns; ++i) { lp[i] = run; run += h[i]; }
        lp[ns] = run;
    }
    __syncthreads();
    if (threadIdx.x < (unsigned)ns) {
        int cb = h[threadIdx.x];
        pos0[threadIdx.x] = cb ? atomicAdd(&cursor[threadIdx.x], cb) : 0;
        h[threadIdx.x] = 0;
    }
    __syncthreads();

    int start = c * CH;
    int cnt = n_edges - start; if (cnt > CH) cnt = CH;

    #pragma unroll
    for (int m = 0; m < 4; ++m) {
        int e = start + (m * 256 + (int)threadIdx.x) * 4;
        if (e + 3 < n_edges) {
            int4 s4 = *(const int4*)(src + e);
            int4 d4 = *(const int4*)(dst + e);
            int ss[4] = {s4.x, s4.y, s4.z, s4.w};
            int dd[4] = {d4.x, d4.y, d4.z, d4.w};
            #pragma unroll
            for (int j = 0; j < 4; ++j) {
                int d = dd[j];
                int sb = d >> SBSHIFT;
                int r = atomicAdd(&h[sb], 1);
                sorted[lp[sb] + r] = ss[j] | ((d & (SBN - 1)) << 17);
            }
        } else {
            int eEnd = e + 4; if (eEnd > n_edges) eEnd = n_edges;
            for (int ee = e; ee < eEnd; ++ee) {
                int d = dst[ee];
                int sb = d >> SBSHIFT;
                int r = atomicAdd(&h[sb], 1);
                sorted[lp[sb] + r] = src[ee] | ((d & (SBN - 1)) << 17);
            }
        }
    }
    __syncthreads();
    for (int p = threadIdx.x; p < cnt; p += 256) {
        int lo = 0, hi = ns;
        while (hi - lo > 1) { int mid = (lo + hi) >> 1; if (lp[mid] <= p) lo = mid; else hi = mid; }
        cpack[pos0[lo] + (p - lp[lo])] = sorted[p];
    }
}

// ---- K4: per-output-chunk degree counts; last block per sb reduces ----------
__global__ __launch_bounds__(256) void chunkDegReduce_kernel(
    const int* __restrict__ cpack, const int* __restrict__ sbsG,
    const int* __restrict__ cstG, int* __restrict__ partialD,
    int* __restrict__ doneD, const float* __restrict__ xw,
    float* __restrict__ degf, float* __restrict__ dinv, float* __restrict__ sxw,
    int n_nodes, int ns)
{
    __shared__ int sbsL[NSMAX + 1], cstL[NSMAX + 1];
    __shared__ int cnt[SBN];
    __shared__ int lastFlag;
    int t = threadIdx.x;
    if (t <= ns) { sbsL[t] = sbsG[t]; cstL[t] = cstG[t]; }
    __syncthreads();
    int c = blockIdx.x;
    if (c >= cstL[ns]) return;
    int lo = 0, hi = ns;
    while (hi - lo > 1) { int mid = (lo + hi) >> 1; if (cstL[mid] <= c) lo = mid; else hi = mid; }
    int sb = lo, i0 = c - cstL[sb];
    int base = sbsL[sb] + i0 * CH;
    int len = sbsL[sb + 1] - base; if (len > CH) len = CH; if (len < 0) len = 0;

    for (int i = t; i < SBN; i += 256) cnt[i] = 0;
    __syncthreads();
    #pragma unroll
    for (int m = 0; m < 4; ++m) {
        int e = (m * 256 + t) * 4;
        if (e + 3 < len) {
            int4 w4 = *(const int4*)(cpack + base + e);
            atomicAdd(&cnt[w4.x >> 17], 1);
            atomicAdd(&cnt[w4.y >> 17], 1);
            atomicAdd(&cnt[w4.z >> 17], 1);
            atomicAdd(&cnt[w4.w >> 17], 1);
        } else {
            int eEnd = e + 4; if (eEnd > len) eEnd = len;
            for (int ee = e; ee < eEnd; ++ee)
                atomicAdd(&cnt[cpack[base + ee] >> 17], 1);
        }
    }
    __syncthreads();
    int* row = partialD + (size_t)c * SBN;
    for (int i = t; i < SBN; i += 256) row[i] = cnt[i];
    __threadfence();
    if (t == 0)
        lastFlag = (atomicAdd(&doneD[sb], 1) == (cstL[sb + 1] - cstL[sb]) - 1);
    __syncthreads();
    if (!lastFlag) return;
    __threadfence();   // acquire
    int c0 = cstL[sb], c1 = cstL[sb + 1];
    int node0 = sb << SBSHIFT;
    for (int li = t; li < SBN; li += 256) {
        int node = node0 + li;
        if (node >= n_nodes) break;
        int d = 0;
        for (int cc = c0; cc < c1; ++cc) d += partialD[(size_t)cc * SBN + li];
        float df = (float)d;
        degf[node] = df;
        float di = rsqrtf(df + 1.0f);   // GCN degree includes self-loop
        dinv[node] = di;
        sxw[node]  = di * xw[node];
    }
}

// ---- K5: per-output-chunk sum of sxw[src]; last block per sb -> epilogue ----
__global__ __launch_bounds__(256) void chunkAccFinal_kernel(
    const int* __restrict__ cpack, const int* __restrict__ sbsG,
    const int* __restrict__ cstG, float* __restrict__ partialF,
    int* __restrict__ doneF, const float* __restrict__ sxw,
    const float* __restrict__ degf, const float* __restrict__ dinv,
    const float* __restrict__ xw, const float* __restrict__ s2dot,
    const float* __restrict__ s3lin,
    const float* __restrict__ alpha, const float* __restrict__ beta,
    const float* __restrict__ Watt, const float* __restrict__ batt,
    float* __restrict__ out, int n_nodes, int ns)
{
    __shared__ int sbsL[NSMAX + 1], cstL[NSMAX + 1];
    __shared__ float facc[SBN];
    __shared__ int lastFlag;
    int t = threadIdx.x;
    if (t <= ns) { sbsL[t] = sbsG[t]; cstL[t] = cstG[t]; }
    __syncthreads();
    int c = blockIdx.x;
    if (c >= cstL[ns]) return;
    int lo = 0, hi = ns;
    while (hi - lo > 1) { int mid = (lo + hi) >> 1; if (cstL[mid] <= c) lo = mid; else hi = mid; }
    int sb = lo, i0 = c - cstL[sb];
    int base = sbsL[sb] + i0 * CH;
    int len = sbsL[sb + 1] - base; if (len > CH) len = CH; if (len < 0) len = 0;

    for (int i = t; i < SBN; i += 256) facc[i] = 0.0f;
    __syncthreads();
    #pragma unroll
    for (int m = 0; m < 4; ++m) {
        int e = (m * 256 + t) * 4;
        if (e + 3 < len) {
            int4 w4 = *(const int4*)(cpack + base + e);
            atomicAdd(&facc[w4.x >> 17], sxw[w4.x & 0x1FFFF]);
            atomicAdd(&facc[w4.y >> 17], sxw[w4.y & 0x1FFFF]);
            atomicAdd(&facc[w4.z >> 17], sxw[w4.z & 0x1FFFF]);
            atomicAdd(&facc[w4.w >> 17], sxw[w4.w & 0x1FFFF]);
        } else {
            int eEnd = e + 4; if (eEnd > len) eEnd = len;
            for (int ee = e; ee < eEnd; ++ee) {
                int w = cpack[base + ee];
                atomicAdd(&facc[w >> 17], sxw[w & 0x1FFFF]);
            }
        }
    }
    __syncthreads();
    float* row = partialF + (size_t)c * SBN;
    for (int i = t; i < SBN; i += 256) row[i] = facc[i];
    __threadfence();
    if (t == 0)
        lastFlag = (atomicAdd(&doneF[sb], 1) == (cstL[sb + 1] - cstL[sb]) - 1);
    __syncthreads();
    if (!lastFlag) return;
    __threadfence();   // acquire
    int c0 = cstL[sb], c1 = cstL[sb + 1];
    int node0 = sb << SBSHIFT;
    float a = alpha[0], b = beta[0];
    for (int li = t; li < SBN; li += 256) {
        int node = node0 + li;
        if (node >= n_nodes) break;
        float acc = 0.0f;
        for (int cc = c0; cc < c1; ++cc) acc += partialF[(size_t)cc * SBN + li];

        float dn = dinv[node];
        float g  = acc * dn + dn * dn * xw[node];  // factored norm + self-loop
        float s1 = sigmoidf_(a * sqrtf(degf[node]) + b);
        float s2 = sigmoidf_(s2dot[node]);
        float s3 = sigmoidf_(g + s3lin[node]);

        float z0 = Watt[0]*s1 + Watt[1]*s2 + Watt[2]*s3 + batt[0];
        float z1 = Watt[3]*s1 + Watt[4]*s2 + Watt[5]*s3 + batt[1];
        float z2 = Watt[6]*s1 + Watt[7]*s2 + Watt[8]*s3 + batt[2];

        float m  = fmaxf(z0, fmaxf(z1, z2));
        float e0 = expf(z0 - m), e1 = expf(z1 - m), e2 = expf(z2 - m);
        float inv = 1.0f / (e0 + e1 + e2);
        out[node] = (e0 * s1 + e1 * s2 + e2 * s3) * inv;
    }
}

extern "C" void kernel_launch(void* const* d_in, const int* in_sizes, int n_in,
                              void* d_out, int out_size, void* d_ws, size_t ws_size,
                              hipStream_t stream) {
    const float* x     = (const float*)d_in[0];
    const int*   ei    = (const int*)d_in[1];
    const float* alpha = (const float*)d_in[2];
    const float* beta  = (const float*)d_in[3];
    const float* Wmlp  = (const float*)d_in[4];
    const float* Wlin  = (const float*)d_in[5];
    const float* Wgcn  = (const float*)d_in[6];
    const float* Watt  = (const float*)d_in[7];
    const float* batt  = (const float*)d_in[8];
    float* out = (float*)d_out;

    int n_nodes = in_sizes[0] / N_CH;
    int n_edges = in_sizes[1] / 2;
    const int* src = ei;
    const int* dst = ei + n_edges;

    int ns  = (n_nodes + SBN - 1) >> SBSHIFT;        // 49
    int nch = (n_edges + CH - 1) / CH;               // 782
    int maxChunks = nch + ns;                        // output-chunk upper bound

    // ws layout (4-byte elements, 1024-aligned big regions)
    size_t off = 0;
    int*   cpack    = (int*)d_ws;          off += (((size_t)n_edges + 1023) & ~(size_t)1023);
    int*   H1       = (int*)d_ws + off;    off += (((size_t)nch * NSMAX + 1023) & ~(size_t)1023);
    int*   sbT      = (int*)d_ws + off;    off += 128;
    int*   sbsG     = (int*)d_ws + off;    off += 128;
    int*   cstG     = (int*)d_ws + off;    off += 128;
    int*   cursor   = (int*)d_ws + off;    off += 128;
    int*   doneD    = (int*)d_ws + off;    off += 128;
    int*   doneF    = (int*)d_ws + off;    off += 128;
    int*   partialD = (int*)d_ws + off;    off += (size_t)maxChunks * SBN;
    float* partialF = (float*)d_ws + off;  off += (size_t)maxChunks * SBN;
    float* s2dot    = (float*)d_ws + off;  off += (((size_t)n_nodes + 1023) & ~(size_t)1023);
    float* s3lin    = (float*)d_ws + off;  off += (((size_t)n_nodes + 1023) & ~(size_t)1023);
    float* xw       = (float*)d_ws + off;  off += (((size_t)n_nodes + 1023) & ~(size_t)1023);
    float* degf     = (float*)d_ws + off;  off += (((size_t)n_nodes + 1023) & ~(size_t)1023);
    float* dinv     = (float*)d_ws + off;  off += (((size_t)n_nodes + 1023) & ~(size_t)1023);
    float* sxw      = (float*)d_ws + off;  off += (((size_t)n_nodes + 1023) & ~(size_t)1023);

    hipMemsetAsync(sbT, 0, 128 * sizeof(int), stream);

    int dotsBlocks = (n_nodes + 31) / 32;            // 4 waves x 8 nodes/block
    dots_hist_kernel<<<nch + dotsBlocks, 256, 0, stream>>>(
        x, Wmlp, Wlin, Wgcn, dst, s2dot, s3lin, xw, H1, sbT,
        n_nodes, n_edges, ns, nch);

    seed_kernel<<<1, 64, 0, stream>>>(sbT, sbsG, cstG, cursor, doneD, doneF, ns);

    scatter_kernel<<<nch, 256, 0, stream>>>(src, dst, H1, cursor, cpack,
                                            n_edges, ns);

    chunkDegReduce_kernel<<<maxChunks, 256, 0, stream>>>(
        cpack, sbsG, cstG, partialD, doneD, xw, degf, dinv, sxw, n_nodes, ns);

    chunkAccFinal_kernel<<<maxChunks, 256, 0, stream>>>(
        cpack, sbsG, cstG, partialF, doneF, sxw, degf, dinv, xw, s2dot, s3lin,
        alpha, beta, Watt, batt, out, n_nodes, ns);
}

// Round 9
// 264.355 us; speedup vs baseline: 1.8358x; 1.8358x over previous
//
#include <hip/hip_runtime.h>
#include <math.h>

#define N_CH    256
#define SBSHIFT 11             // super-bucket = 2048 nodes
#define SBN     2048
#define NSMAX   64             // actual ns = 49
#define CH      4096           // edges per chunk (input and output chunks)

__device__ __forceinline__ float sigmoidf_(float v) {
    return 1.0f / (1.0f + expf(-v));
}

// ---- K1: blocks [0,nch) histogram one 4096-edge chunk into 49 coarse bins
// ---- (row -> H1, totals -> sbT atomics); remaining blocks: per-node dots,
// ---- 4 waves/block x 8 nodes/wave with weights held in registers -----------
__global__ __launch_bounds__(256) void dots_hist_kernel(
    const float* __restrict__ x,
    const float* __restrict__ Wmlp, const float* __restrict__ Wlin,
    const float* __restrict__ Wgcn, const int* __restrict__ dst,
    float* __restrict__ s2dot, float* __restrict__ s3lin, float* __restrict__ xw,
    int* __restrict__ H1, int* __restrict__ sbT,
    int n_nodes, int n_edges, int ns, int nch)
{
    __shared__ int h[NSMAX];
    if ((int)blockIdx.x < nch) {
        int c = blockIdx.x;
        if (threadIdx.x < NSMAX) h[threadIdx.x] = 0;
        __syncthreads();
        int start = c * CH;
        #pragma unroll
        for (int m = 0; m < 4; ++m) {
            int e = start + (m * 256 + (int)threadIdx.x) * 4;
            if (e + 3 < n_edges) {
                int4 d4 = *(const int4*)(dst + e);
                atomicAdd(&h[d4.x >> SBSHIFT], 1);
                atomicAdd(&h[d4.y >> SBSHIFT], 1);
                atomicAdd(&h[d4.z >> SBSHIFT], 1);
                atomicAdd(&h[d4.w >> SBSHIFT], 1);
            } else {
                int eEnd = e + 4; if (eEnd > n_edges) eEnd = n_edges;
                for (int ee = e; ee < eEnd; ++ee)
                    atomicAdd(&h[dst[ee] >> SBSHIFT], 1);
            }
        }
        __syncthreads();
        if (threadIdx.x < NSMAX) {
            int v = (threadIdx.x < (unsigned)ns) ? h[threadIdx.x] : 0;
            H1[(size_t)c * NSMAX + threadIdx.x] = v;
            if (v) atomicAdd(&sbT[threadIdx.x], v);
        }
        return;
    }

    int wave = ((int)blockIdx.x - nch) * 4 + ((int)threadIdx.x >> 6);
    int lane = threadIdx.x & 63;
    int n0 = wave * 8;
    if (n0 >= n_nodes) return;
    float4 wm = ((const float4*)Wmlp)[lane];
    float4 wl = ((const float4*)Wlin)[lane];
    float4 wg = ((const float4*)Wgcn)[lane];
    int nEnd = n0 + 8; if (nEnd > n_nodes) nEnd = n_nodes;
    for (int node = n0; node < nEnd; ++node) {
        float4 v = ((const float4*)(x + (size_t)node * N_CH))[lane];
        float d0 = v.x*wm.x + v.y*wm.y + v.z*wm.z + v.w*wm.w;
        float d1 = v.x*wl.x + v.y*wl.y + v.z*wl.z + v.w*wl.w;
        float d2 = v.x*wg.x + v.y*wg.y + v.z*wg.z + v.w*wg.w;
        #pragma unroll
        for (int off = 32; off; off >>= 1) {
            d0 += __shfl_down(d0, off, 64);
            d1 += __shfl_down(d1, off, 64);
            d2 += __shfl_down(d2, off, 64);
        }
        if (lane == 0) { s2dot[node] = d0; s3lin[node] = d1; xw[node] = d2; }
    }
}

// ---- K2: tiny seed (1 block): sbs/cst tables + scatter cursors --------------
__global__ __launch_bounds__(64) void seed_kernel(
    const int* __restrict__ sbT, int* __restrict__ sbsG, int* __restrict__ cstG,
    int* __restrict__ cursor, int ns)
{
    __shared__ int sbsL[NSMAX + 1], cstL[NSMAX + 1];
    if (threadIdx.x == 0) {
        int run = 0, c = 0;
        for (int i = 0; i < ns; ++i) {
            sbsL[i] = run; cstL[i] = c;
            int len = sbT[i];
            run += len;
            c += (len + CH - 1) / CH;
        }
        sbsL[ns] = run; cstL[ns] = c;
    }
    __syncthreads();
    int t = threadIdx.x;
    if (t <= ns) { sbsG[t] = sbsL[t]; cstG[t] = cstL[t]; }
    if (t < ns)  cursor[t] = sbsL[t];
}

// ---- K3: scatter — H1-seeded LDS counting sort, cursor-reserved flush -------
// cpack word: src (17 bits) | local11 (11 bits) << 17
__global__ __launch_bounds__(256) void scatter_kernel(
    const int* __restrict__ src, const int* __restrict__ dst,
    const int* __restrict__ H1, int* __restrict__ cursor,
    int* __restrict__ cpack, int n_edges, int ns)
{
    __shared__ int lp[NSMAX + 1];      // local exclusive prefix
    __shared__ int h[NSMAX];           // rank counters
    __shared__ int pos0[NSMAX];        // reserved global base per sb
    __shared__ int sorted[CH];         // 16 KB

    int c = blockIdx.x;
    if (threadIdx.x < NSMAX) h[threadIdx.x] = H1[(size_t)c * NSMAX + threadIdx.x];
    __syncthreads();
    if (threadIdx.x == 0) {
        int run = 0;
        for (int i = 0; i < ns; ++i) { lp[i] = run; run += h[i]; }
        lp[ns] = run;
    }
    __syncthreads();
    if (threadIdx.x < (unsigned)ns) {
        int cb = h[threadIdx.x];
        pos0[threadIdx.x] = cb ? atomicAdd(&cursor[threadIdx.x], cb) : 0;
        h[threadIdx.x] = 0;
    }
    __syncthreads();

    int start = c * CH;
    int cnt = n_edges - start; if (cnt > CH) cnt = CH;

    #pragma unroll
    for (int m = 0; m < 4; ++m) {
        int e = start + (m * 256 + (int)threadIdx.x) * 4;
        if (e + 3 < n_edges) {
            int4 s4 = *(const int4*)(src + e);
            int4 d4 = *(const int4*)(dst + e);
            int ss[4] = {s4.x, s4.y, s4.z, s4.w};
            int dd[4] = {d4.x, d4.y, d4.z, d4.w};
            #pragma unroll
            for (int j = 0; j < 4; ++j) {
                int d = dd[j];
                int sb = d >> SBSHIFT;
                int r = atomicAdd(&h[sb], 1);
                sorted[lp[sb] + r] = ss[j] | ((d & (SBN - 1)) << 17);
            }
        } else {
            int eEnd = e + 4; if (eEnd > n_edges) eEnd = n_edges;
            for (int ee = e; ee < eEnd; ++ee) {
                int d = dst[ee];
                int sb = d >> SBSHIFT;
                int r = atomicAdd(&h[sb], 1);
                sorted[lp[sb] + r] = src[ee] | ((d & (SBN - 1)) << 17);
            }
        }
    }
    __syncthreads();
    for (int p = threadIdx.x; p < cnt; p += 256) {
        int lo = 0, hi = ns;
        while (hi - lo > 1) { int mid = (lo + hi) >> 1; if (lp[mid] <= p) lo = mid; else hi = mid; }
        cpack[pos0[lo] + (p - lp[lo])] = sorted[p];
    }
}

// ---- K4: per-output-chunk node counts -> dense partial rows -----------------
__global__ __launch_bounds__(256) void chunkDeg_kernel(
    const int* __restrict__ cpack, const int* __restrict__ sbsG,
    const int* __restrict__ cstG, int* __restrict__ partialD, int ns)
{
    __shared__ int sbsL[NSMAX + 1], cstL[NSMAX + 1];
    __shared__ int cnt[SBN];
    int t = threadIdx.x;
    if (t <= ns) { sbsL[t] = sbsG[t]; cstL[t] = cstG[t]; }
    for (int i = t; i < SBN; i += 256) cnt[i] = 0;
    __syncthreads();
    int c = blockIdx.x;
    if (c >= cstL[ns]) return;
    int lo = 0, hi = ns;
    while (hi - lo > 1) { int mid = (lo + hi) >> 1; if (cstL[mid] <= c) lo = mid; else hi = mid; }
    int sb = lo, i0 = c - cstL[sb];
    int base = sbsL[sb] + i0 * CH;
    int len = sbsL[sb + 1] - base; if (len > CH) len = CH;

    #pragma unroll
    for (int m = 0; m < 4; ++m) {
        int e = (m * 256 + t) * 4;
        if (e + 3 < len) {
            int4 w4 = *(const int4*)(cpack + base + e);
            atomicAdd(&cnt[w4.x >> 17], 1);
            atomicAdd(&cnt[w4.y >> 17], 1);
            atomicAdd(&cnt[w4.z >> 17], 1);
            atomicAdd(&cnt[w4.w >> 17], 1);
        } else {
            int eEnd = e + 4; if (eEnd > len) eEnd = len;
            for (int ee = e; ee < eEnd; ++ee)
                atomicAdd(&cnt[cpack[base + ee] >> 17], 1);
        }
    }
    __syncthreads();
    int* row = partialD + (size_t)c * SBN;
    for (int i = t; i < SBN; i += 256) row[i] = cnt[i];
}

// ---- K5: per-node degree -> degf, dinv, sxw ---------------------------------
__global__ __launch_bounds__(256) void reduceDeg_kernel(
    const int* __restrict__ partialD, const int* __restrict__ cstG,
    const float* __restrict__ xw,
    float* __restrict__ degf, float* __restrict__ dinv, float* __restrict__ sxw,
    int n_nodes)
{
    int i = blockIdx.x * 256 + threadIdx.x;
    if (i >= n_nodes) return;
    int sb = i >> SBSHIFT, li = i & (SBN - 1);
    int c0 = cstG[sb], c1 = cstG[sb + 1];
    int d = 0;
    for (int c = c0; c < c1; ++c) d += partialD[(size_t)c * SBN + li];
    float df = (float)d;
    degf[i] = df;
    float di = rsqrtf(df + 1.0f);        // GCN degree includes self-loop
    dinv[i] = di;
    sxw[i]  = di * xw[i];
}

// ---- K6: per-output-chunk sum of sxw[src] -> dense partial rows -------------
__global__ __launch_bounds__(256) void chunkAcc_kernel(
    const int* __restrict__ cpack, const int* __restrict__ sbsG,
    const int* __restrict__ cstG, const float* __restrict__ sxw,
    float* __restrict__ partialF, int ns)
{
    __shared__ int sbsL[NSMAX + 1], cstL[NSMAX + 1];
    __shared__ float facc[SBN];
    int t = threadIdx.x;
    if (t <= ns) { sbsL[t] = sbsG[t]; cstL[t] = cstG[t]; }
    for (int i = t; i < SBN; i += 256) facc[i] = 0.0f;
    __syncthreads();
    int c = blockIdx.x;
    if (c >= cstL[ns]) return;
    int lo = 0, hi = ns;
    while (hi - lo > 1) { int mid = (lo + hi) >> 1; if (cstL[mid] <= c) lo = mid; else hi = mid; }
    int sb = lo, i0 = c - cstL[sb];
    int base = sbsL[sb] + i0 * CH;
    int len = sbsL[sb + 1] - base; if (len > CH) len = CH;

    #pragma unroll
    for (int m = 0; m < 4; ++m) {
        int e = (m * 256 + t) * 4;
        if (e + 3 < len) {
            int4 w4 = *(const int4*)(cpack + base + e);
            atomicAdd(&facc[w4.x >> 17], sxw[w4.x & 0x1FFFF]);
            atomicAdd(&facc[w4.y >> 17], sxw[w4.y & 0x1FFFF]);
            atomicAdd(&facc[w4.z >> 17], sxw[w4.z & 0x1FFFF]);
            atomicAdd(&facc[w4.w >> 17], sxw[w4.w & 0x1FFFF]);
        } else {
            int eEnd = e + 4; if (eEnd > len) eEnd = len;
            for (int ee = e; ee < eEnd; ++ee) {
                int w = cpack[base + ee];
                atomicAdd(&facc[w >> 17], sxw[w & 0x1FFFF]);
            }
        }
    }
    __syncthreads();
    float* row = partialF + (size_t)c * SBN;
    for (int i = t; i < SBN; i += 256) row[i] = facc[i];
}

// ---- K7: per-node accumulate + fused epilogue -------------------------------
__global__ __launch_bounds__(256) void reduceFinal_kernel(
    const float* __restrict__ partialF, const int* __restrict__ cstG,
    const float* __restrict__ degf, const float* __restrict__ dinv,
    const float* __restrict__ xw, const float* __restrict__ s2dot,
    const float* __restrict__ s3lin,
    const float* __restrict__ alpha, const float* __restrict__ beta,
    const float* __restrict__ Watt, const float* __restrict__ batt,
    float* __restrict__ out, int n_nodes)
{
    int i = blockIdx.x * 256 + threadIdx.x;
    if (i >= n_nodes) return;
    int sb = i >> SBSHIFT, li = i & (SBN - 1);
    int c0 = cstG[sb], c1 = cstG[sb + 1];
    float acc = 0.0f;
    for (int c = c0; c < c1; ++c) acc += partialF[(size_t)c * SBN + li];

    float dn = dinv[i];
    float g  = acc * dn + dn * dn * xw[i];     // factored norm + self-loop
    float s1 = sigmoidf_(alpha[0] * sqrtf(degf[i]) + beta[0]);
    float s2 = sigmoidf_(s2dot[i]);
    float s3 = sigmoidf_(g + s3lin[i]);

    float z0 = Watt[0]*s1 + Watt[1]*s2 + Watt[2]*s3 + batt[0];
    float z1 = Watt[3]*s1 + Watt[4]*s2 + Watt[5]*s3 + batt[1];
    float z2 = Watt[6]*s1 + Watt[7]*s2 + Watt[8]*s3 + batt[2];

    float m  = fmaxf(z0, fmaxf(z1, z2));
    float e0 = expf(z0 - m), e1 = expf(z1 - m), e2 = expf(z2 - m);
    float inv = 1.0f / (e0 + e1 + e2);
    out[i] = (e0 * s1 + e1 * s2 + e2 * s3) * inv;
}

extern "C" void kernel_launch(void* const* d_in, const int* in_sizes, int n_in,
                              void* d_out, int out_size, void* d_ws, size_t ws_size,
                              hipStream_t stream) {
    const float* x     = (const float*)d_in[0];
    const int*   ei    = (const int*)d_in[1];
    const float* alpha = (const float*)d_in[2];
    const float* beta  = (const float*)d_in[3];
    const float* Wmlp  = (const float*)d_in[4];
    const float* Wlin  = (const float*)d_in[5];
    const float* Wgcn  = (const float*)d_in[6];
    const float* Watt  = (const float*)d_in[7];
    const float* batt  = (const float*)d_in[8];
    float* out = (float*)d_out;

    int n_nodes = in_sizes[0] / N_CH;
    int n_edges = in_sizes[1] / 2;
    const int* src = ei;
    const int* dst = ei + n_edges;

    int ns  = (n_nodes + SBN - 1) >> SBSHIFT;        // 49
    int nch = (n_edges + CH - 1) / CH;               // 782
    int maxChunks = nch + ns;                        // output-chunk upper bound

    // ws layout (4-byte elements, 1024-aligned big regions)
    size_t off = 0;
    int*   cpack    = (int*)d_ws;          off += (((size_t)n_edges + 1023) & ~(size_t)1023);
    int*   H1       = (int*)d_ws + off;    off += (((size_t)nch * NSMAX + 1023) & ~(size_t)1023);
    int*   sbT      = (int*)d_ws + off;    off += 128;
    int*   sbsG     = (int*)d_ws + off;    off += 128;
    int*   cstG     = (int*)d_ws + off;    off += 128;
    int*   cursor   = (int*)d_ws + off;    off += 128;
    int*   partialD = (int*)d_ws + off;    off += (size_t)maxChunks * SBN;
    float* partialF = (float*)d_ws + off;  off += (size_t)maxChunks * SBN;
    float* s2dot    = (float*)d_ws + off;  off += (((size_t)n_nodes + 1023) & ~(size_t)1023);
    float* s3lin    = (float*)d_ws + off;  off += (((size_t)n_nodes + 1023) & ~(size_t)1023);
    float* xw       = (float*)d_ws + off;  off += (((size_t)n_nodes + 1023) & ~(size_t)1023);
    float* degf     = (float*)d_ws + off;  off += (((size_t)n_nodes + 1023) & ~(size_t)1023);
    float* dinv     = (float*)d_ws + off;  off += (((size_t)n_nodes + 1023) & ~(size_t)1023);
    float* sxw      = (float*)d_ws + off;  off += (((size_t)n_nodes + 1023) & ~(size_t)1023);

    hipMemsetAsync(sbT, 0, 128 * sizeof(int), stream);

    int dotsBlocks = (n_nodes + 31) / 32;            // 4 waves x 8 nodes/block
    dots_hist_kernel<<<nch + dotsBlocks, 256, 0, stream>>>(
        x, Wmlp, Wlin, Wgcn, dst, s2dot, s3lin, xw, H1, sbT,
        n_nodes, n_edges, ns, nch);

    seed_kernel<<<1, 64, 0, stream>>>(sbT, sbsG, cstG, cursor, ns);

    scatter_kernel<<<nch, 256, 0, stream>>>(src, dst, H1, cursor, cpack,
                                            n_edges, ns);

    chunkDeg_kernel<<<maxChunks, 256, 0, stream>>>(cpack, sbsG, cstG, partialD, ns);

    reduceDeg_kernel<<<(n_nodes + 255) / 256, 256, 0, stream>>>(
        partialD, cstG, xw, degf, dinv, sxw, n_nodes);

    chunkAcc_kernel<<<maxChunks, 256, 0, stream>>>(cpack, sbsG, cstG, sxw,
                                                   partialF, ns);

    reduceFinal_kernel<<<(n_nodes + 255) / 256, 256, 0, stream>>>(
        partialF, cstG, degf, dinv, xw, s2dot, s3lin,
        alpha, beta, Watt, batt, out, n_nodes);
}